// Round 11
// baseline (778.898 us; speedup 1.0000x reference)
//
#include <hip/hip_runtime.h>
#include <hip/hip_bf16.h>

#define NV 778
#define NJ 16
#define NBETA 10
#define NP 135
#define NTHETA 15
#define SD_COLS 2334   // NV*3
#define NBAT 8         // batches per block

__device__ __constant__ int c_par[16] = {-1,0,1,2,0,4,5,0,7,8,0,10,11,0,13,14};

// ---------------- Kernel 1: SJ[k][j][c] (10x16x3) and Jt[j][c] (16x3) ----------------
__global__ __launch_bounds__(64) void k_prejoint(
    const float* __restrict__ sd, const float* __restrict__ vt,
    const float* __restrict__ Jr, float* __restrict__ SJ, float* __restrict__ Jt)
{
    const int o = blockIdx.x;
    const int t = threadIdx.x;
    float acc = 0.f;
    if (o < 480) {
        int k = o / 48, rem = o % 48, j = rem / 3, c = rem % 3;
        for (int v = t; v < NV; v += 64) acc += sd[k * SD_COLS + v * 3 + c] * Jr[v * NJ + j];
    } else {
        int idx = o - 480, j = idx / 3, c = idx % 3;
        for (int v = t; v < NV; v += 64) acc += vt[v * 3 + c] * Jr[v * NJ + j];
    }
    #pragma unroll
    for (int off = 32; off > 0; off >>= 1) acc += __shfl_down(acc, off);
    if (t == 0) {
        if (o < 480) SJ[o] = acc;
        else Jt[o - 480] = acc;
    }
}

// ---------------- Kernel 2 (fused, 512 threads): pose prologue + verts + joints -----
// 1024 blocks x 512 thr (8 waves). LDS 36.3KB -> 4 blocks/CU x 8 waves = 32 waves/CU
// (100% cap; round-10's 256-thr version was grid-capped at 16). Joint reduction stages
// 256-row half-tiles so vertLDS stays 25.6KB.
__global__ __launch_bounds__(512, 6) void k_fused(
    const float* __restrict__ beta, const float* __restrict__ theta,
    const float* __restrict__ sd, const float* __restrict__ pd,
    const float* __restrict__ vt, const float* __restrict__ Jr,
    const float* __restrict__ W, const float* __restrict__ hm,
    const float* __restrict__ hc, const float* __restrict__ SJ,
    const float* __restrict__ Jt, float* __restrict__ out)
{
    // LDS plan (36,096 B):
    //   [0, 25600)        vertLDS[256][25]  (reduction staging)  OVERLAYS prologue th/Rsh/JL
    //   [25600, 31744)    A_lds[8][16][12]
    //   [31744, 36096)    pf_lds[135][8]
    __shared__ __align__(16) char smem[25600 + 6144 + 4352];
    float* const vertLDS = (float*)smem;
    float* const A_lds   = (float*)(smem + 25600);
    float* const pf_lds  = (float*)(smem + 25600 + 6144);
    float* const th  = (float*)smem;                   // [8][48]
    float* const Rsh = (float*)(smem + 1536);          // [8][16][9]
    float* const JLs = (float*)(smem + 1536 + 4608);   // [8][16][3]

    const int tid = threadIdx.x;
    const int bbase = blockIdx.x * NBAT;

    // ---- prologue phase 1: full pose th[b][0..47] ----
    if (tid < NBAT * 48) {
        int b = tid / 48, i = tid % 48;
        float acc;
        if (i < 3) {
            acc = theta[(size_t)(bbase + b) * NTHETA + i];
        } else {
            acc = hm[i - 3];
            #pragma unroll
            for (int k = 0; k < 12; ++k)
                acc += theta[(size_t)(bbase + b) * NTHETA + 3 + k] * hc[k * 45 + (i - 3)];
        }
        th[b * 48 + i] = acc;
    }
    __syncthreads();

    // ---- phase 2: Rodrigues (R) + joint positions (JL) per (b, j) ----
    if (tid < NBAT * 16) {
        int b = tid >> 4, j = tid & 15;
        float tx = th[b * 48 + 3 * j], ty = th[b * 48 + 3 * j + 1], tz = th[b * 48 + 3 * j + 2];
        float px = tx + 1e-8f, py = ty + 1e-8f, pz = tz + 1e-8f;
        float ang = sqrtf(px * px + py * py + pz * pz);
        float nx = tx / ang, ny = ty / ang, nz = tz / ang;
        float half = 0.5f * ang;
        float w = cosf(half), s = sinf(half);
        float qx = s * nx, qy = s * ny, qz = s * nz;
        float qn = sqrtf(w * w + qx * qx + qy * qy + qz * qz);
        w /= qn; qx /= qn; qy /= qn; qz /= qn;
        float w2 = w * w, x2 = qx * qx, y2 = qy * qy, z2 = qz * qz;
        float wx = w * qx, wy = w * qy, wz = w * qz;
        float xy = qx * qy, xz = qx * qz, yz = qy * qz;
        float* R = Rsh + (b * 16 + j) * 9;
        R[0] = w2 + x2 - y2 - z2; R[1] = 2.f * xy - 2.f * wz; R[2] = 2.f * wy + 2.f * xz;
        R[3] = 2.f * wz + 2.f * xy; R[4] = w2 - x2 + y2 - z2; R[5] = 2.f * yz - 2.f * wx;
        R[6] = 2.f * xz - 2.f * wy; R[7] = 2.f * wx + 2.f * yz; R[8] = w2 - x2 - y2 + z2;
        #pragma unroll
        for (int c = 0; c < 3; ++c) {
            float acc = Jt[j * 3 + c];
            #pragma unroll
            for (int k = 0; k < NBETA; ++k)
                acc += beta[(size_t)(bbase + b) * NBETA + k] * SJ[k * 48 + j * 3 + c];
            JLs[(b * 16 + j) * 3 + c] = acc;
        }
    }
    __syncthreads();

    // ---- phase 3: kinematic chain -> A_lds; pose_feature -> pf_lds ----
    if (tid < NBAT * 16) {
        int b = tid >> 4, j = tid & 15;
        int path[4]; int d = 0; int i = j;
        while (i >= 0) { path[d++] = i; i = c_par[i]; }
        float GR[9], Gt3[3];
        #pragma unroll
        for (int e = 0; e < 9; ++e) GR[e] = Rsh[(b * 16 + 0) * 9 + e];
        Gt3[0] = JLs[(b * 16) * 3 + 0]; Gt3[1] = JLs[(b * 16) * 3 + 1]; Gt3[2] = JLs[(b * 16) * 3 + 2];
        for (int s2 = d - 2; s2 >= 0; --s2) {
            int i2 = path[s2];
            int pa = c_par[i2];
            float ti0 = JLs[(b * 16 + i2) * 3 + 0] - JLs[(b * 16 + pa) * 3 + 0];
            float ti1 = JLs[(b * 16 + i2) * 3 + 1] - JLs[(b * 16 + pa) * 3 + 1];
            float ti2 = JLs[(b * 16 + i2) * 3 + 2] - JLs[(b * 16 + pa) * 3 + 2];
            const float* Ri = Rsh + (b * 16 + i2) * 9;
            float NR[9], Nt[3];
            #pragma unroll
            for (int r = 0; r < 3; ++r) {
                #pragma unroll
                for (int c = 0; c < 3; ++c) {
                    NR[r * 3 + c] = GR[r * 3 + 0] * Ri[0 * 3 + c]
                                  + GR[r * 3 + 1] * Ri[1 * 3 + c]
                                  + GR[r * 3 + 2] * Ri[2 * 3 + c];
                }
                Nt[r] = GR[r * 3 + 0] * ti0 + GR[r * 3 + 1] * ti1 + GR[r * 3 + 2] * ti2 + Gt3[r];
            }
            #pragma unroll
            for (int e = 0; e < 9; ++e) GR[e] = NR[e];
            Gt3[0] = Nt[0]; Gt3[1] = Nt[1]; Gt3[2] = Nt[2];
        }
        float jx = JLs[(b * 16 + j) * 3 + 0], jy = JLs[(b * 16 + j) * 3 + 1], jz = JLs[(b * 16 + j) * 3 + 2];
        float* A = A_lds + (b * 16 + j) * 12;
        #pragma unroll
        for (int r = 0; r < 3; ++r) {
            A[r * 4 + 0] = GR[r * 3 + 0];
            A[r * 4 + 1] = GR[r * 3 + 1];
            A[r * 4 + 2] = GR[r * 3 + 2];
            A[r * 4 + 3] = Gt3[r] - (GR[r * 3 + 0] * jx + GR[r * 3 + 1] * jy + GR[r * 3 + 2] * jz);
        }
        if (j > 0) {
            #pragma unroll
            for (int e = 0; e < 9; ++e) {
                float dlt = (e == 0 || e == 4 || e == 8) ? 1.f : 0.f;
                pf_lds[((j - 1) * 9 + e) * NBAT + b] = Rsh[(b * 16 + j) * 9 + e] - dlt;
            }
        }
    }
    __syncthreads();   // prologue scratch dead; vertLDS region free

    // ---- main loop: 2 vertex tiles of 512 ----
    const int rb = tid & 7;
    const int rj = (tid >> 3) & 15;
    const int quarter = (tid >> 7) & 3;
    float jacc0 = 0.f, jacc1 = 0.f, jacc2 = 0.f;

    for (int tile = 0; tile < 2; ++tile) {
        const int vbase = tile * 512;
        const int v = vbase + tid;
        const bool valid = v < NV;
        float vx[NBAT], vy[NBAT], vz[NBAT];
        float wrow[NJ];

        if (valid) {
            float sdc0[NBETA], sdc1[NBETA], sdc2[NBETA];
            #pragma unroll
            for (int k = 0; k < NBETA; ++k) {
                sdc0[k] = sd[k * SD_COLS + v * 3 + 0];
                sdc1[k] = sd[k * SD_COLS + v * 3 + 1];
                sdc2[k] = sd[k * SD_COLS + v * 3 + 2];
            }
            float vt0 = vt[v * 3 + 0], vt1 = vt[v * 3 + 1], vt2 = vt[v * 3 + 2];
            #pragma unroll
            for (int b = 0; b < NBAT; ++b) {
                float ax = vt0, ay = vt1, az = vt2;
                #pragma unroll
                for (int k = 0; k < NBETA; ++k) {
                    float be = beta[(size_t)(bbase + b) * NBETA + k];   // uniform -> s_load
                    ax += be * sdc0[k]; ay += be * sdc1[k]; az += be * sdc2[k];
                }
                vx[b] = ax; vy[b] = ay; vz[b] = az;
            }
            // pose-blend: pf from LDS broadcast
            for (int p = 0; p < NP; ++p) {
                float p0 = pd[p * SD_COLS + v * 3 + 0];
                float p1 = pd[p * SD_COLS + v * 3 + 1];
                float p2 = pd[p * SD_COLS + v * 3 + 2];
                #pragma unroll
                for (int b = 0; b < NBAT; ++b) {
                    float f = pf_lds[p * NBAT + b];
                    vx[b] += f * p0; vy[b] += f * p1; vz[b] += f * p2;
                }
            }
            #pragma unroll
            for (int j = 0; j < NJ; ++j) wrow[j] = W[v * NJ + j];
        } else {
            #pragma unroll
            for (int b = 0; b < NBAT; ++b) { vx[b] = 0.f; vy[b] = 0.f; vz[b] = 0.f; }
            #pragma unroll
            for (int j = 0; j < NJ; ++j) wrow[j] = 0.f;
        }

        // skinning from LDS-resident A
        #pragma unroll
        for (int b = 0; b < NBAT; ++b) {
            const float* Ab = A_lds + b * 192;
            float ax = 0.f, ay = 0.f, az = 0.f;
            #pragma unroll
            for (int j = 0; j < NJ; ++j) {
                const float* Aj = Ab + j * 12;
                float wj = wrow[j];
                float s0 = Aj[3];  s0 += Aj[0] * vx[b]; s0 += Aj[1]  * vy[b]; s0 += Aj[2]  * vz[b];
                float s1 = Aj[7];  s1 += Aj[4] * vx[b]; s1 += Aj[5]  * vy[b]; s1 += Aj[6]  * vz[b];
                float s2 = Aj[11]; s2 += Aj[8] * vx[b]; s2 += Aj[9]  * vy[b]; s2 += Aj[10] * vz[b];
                ax += wj * s0; ay += wj * s1; az += wj * s2;
            }
            vx[b] = ax; vy[b] = ay; vz[b] = az;
        }

        // finger vertices -> direct output (float32)
        if (valid) {
            int f = (v == 734) ? 0 : (v == 333) ? 1 : (v == 443) ? 2 : (v == 555) ? 3 : (v == 678) ? 4 : -1;
            if (f >= 0) {
                #pragma unroll
                for (int b = 0; b < NBAT; ++b) {
                    size_t o = (size_t)(bbase + b) * 63 + (size_t)(16 + f) * 3;
                    out[o + 0] = vx[b];
                    out[o + 1] = vy[b];
                    out[o + 2] = vz[b];
                }
            }
        }

        // two stage+reduce sub-phases of 256 rows each
        #pragma unroll
        for (int sh = 0; sh < 2; ++sh) {
            if ((tid >> 8) == sh) {
                int r = tid & 255;
                #pragma unroll
                for (int b = 0; b < NBAT; ++b) {
                    vertLDS[r * 25 + b * 3 + 0] = vx[b];
                    vertLDS[r * 25 + b * 3 + 1] = vy[b];
                    vertLDS[r * 25 + b * 3 + 2] = vz[b];
                }
            }
            __syncthreads();
            int lim = NV - vbase - sh * 256;
            if (lim > 256) lim = 256;
            if (lim < 0) lim = 0;
            int lo = quarter * 64;
            int hi = lo + 64; if (hi > lim) hi = lim;
            const int rowbase = vbase + sh * 256;
            #pragma unroll 4
            for (int vv = lo; vv < hi; ++vv) {
                float jr = Jr[(size_t)(rowbase + vv) * NJ + rj];
                jacc0 += jr * vertLDS[vv * 25 + rb * 3 + 0];
                jacc1 += jr * vertLDS[vv * 25 + rb * 3 + 1];
                jacc2 += jr * vertLDS[vv * 25 + rb * 3 + 2];
            }
            __syncthreads();
        }
    }

    // combine the 4 quarters' partials via LDS (reuse vertLDS: 512*3 floats = 6KB)
    vertLDS[tid * 3 + 0] = jacc0;
    vertLDS[tid * 3 + 1] = jacc1;
    vertLDS[tid * 3 + 2] = jacc2;
    __syncthreads();
    if (tid < 128) {
        float j0 = 0.f, j1 = 0.f, j2 = 0.f;
        #pragma unroll
        for (int q = 0; q < 4; ++q) {
            j0 += vertLDS[(tid + q * 128) * 3 + 0];
            j1 += vertLDS[(tid + q * 128) * 3 + 1];
            j2 += vertLDS[(tid + q * 128) * 3 + 2];
        }
        size_t o = (size_t)(bbase + rb) * 63 + (size_t)rj * 3;
        out[o + 0] = j0;
        out[o + 1] = j1;
        out[o + 2] = j2;
    }
}

extern "C" void kernel_launch(void* const* d_in, const int* in_sizes, int n_in,
                              void* d_out, int out_size, void* d_ws, size_t ws_size,
                              hipStream_t stream) {
    const float* beta = (const float*)d_in[0];
    const float* theta = (const float*)d_in[1];
    const float* sd   = (const float*)d_in[2];
    const float* pd   = (const float*)d_in[3];
    const float* vt   = (const float*)d_in[4];
    const float* Jr   = (const float*)d_in[5];
    const float* W    = (const float*)d_in[6];
    const float* hm   = (const float*)d_in[7];
    const float* hc   = (const float*)d_in[8];
    float* out = (float*)d_out;

    const int B = in_sizes[0] / NBETA;   // 8192

    float* SJ = (float*)d_ws;            // 480
    float* Jt = SJ + 480;                // 48

    k_prejoint<<<528, 64, 0, stream>>>(sd, vt, Jr, SJ, Jt);
    k_fused<<<B / NBAT, 512, 0, stream>>>(beta, theta, sd, pd, vt, Jr, W, hm, hc, SJ, Jt, out);
}

// Round 12
// 518.448 us; speedup vs baseline: 1.5024x; 1.5024x over previous
//
#include <hip/hip_runtime.h>
#include <hip/hip_bf16.h>

#define NV 778
#define NJ 16
#define NBETA 10
#define NP 135
#define NTHETA 15
#define SD_COLS 2334   // NV*3
#define NBAT 8         // batches per block

__device__ __constant__ int c_par[16] = {-1,0,1,2,0,4,5,0,7,8,0,10,11,0,13,14};

// ---------------- Kernel 1: SJ[k][j][c] (10x16x3) and Jt[j][c] (16x3) ----------------
__global__ __launch_bounds__(64) void k_prejoint(
    const float* __restrict__ sd, const float* __restrict__ vt,
    const float* __restrict__ Jr, float* __restrict__ SJ, float* __restrict__ Jt)
{
    const int o = blockIdx.x;
    const int t = threadIdx.x;
    float acc = 0.f;
    if (o < 480) {
        int k = o / 48, rem = o % 48, j = rem / 3, c = rem % 3;
        for (int v = t; v < NV; v += 64) acc += sd[k * SD_COLS + v * 3 + c] * Jr[v * NJ + j];
    } else {
        int idx = o - 480, j = idx / 3, c = idx % 3;
        for (int v = t; v < NV; v += 64) acc += vt[v * 3 + c] * Jr[v * NJ + j];
    }
    #pragma unroll
    for (int off = 32; off > 0; off >>= 1) acc += __shfl_down(acc, off);
    if (t == 0) {
        if (o < 480) SJ[o] = acc;
        else Jt[o - 480] = acc;
    }
}

// ---------------- Kernel 2 (fused): pose prologue + vertices + skinning + joints ----
// 1024 blocks x 256 thr. NO min-waves clamp: round 10/11 showed __launch_bounds__
// second arg forces VGPR down and the ~85-float live state spills to scratch
// (WRITE_SIZE 299MB->1GB). Cap 256 VGPR; LDS 36.3KB caps 4 blocks/CU = 16 waves/CU,
// which VGPR<=128 already permits. Shape-blend restructured k-outer to trim 30 live regs.
__global__ __launch_bounds__(256) void k_fused(
    const float* __restrict__ beta, const float* __restrict__ theta,
    const float* __restrict__ sd, const float* __restrict__ pd,
    const float* __restrict__ vt, const float* __restrict__ Jr,
    const float* __restrict__ W, const float* __restrict__ hm,
    const float* __restrict__ hc, const float* __restrict__ SJ,
    const float* __restrict__ Jt, float* __restrict__ out)
{
    // LDS plan (36,096 B):
    //   [0, 25600)        vertLDS[256][25]  (reduction staging)  OVERLAYS prologue th/Rsh/JL
    //   [25600, 31744)    A_lds[8][16][12]
    //   [31744, 36096)    pf_lds[135][8]
    __shared__ __align__(16) char smem[25600 + 6144 + 4352];
    float* const vertLDS = (float*)smem;
    float* const A_lds   = (float*)(smem + 25600);
    float* const pf_lds  = (float*)(smem + 25600 + 6144);
    float* const th  = (float*)smem;                   // [8][48]
    float* const Rsh = (float*)(smem + 1536);          // [8][16][9]
    float* const JLs = (float*)(smem + 1536 + 4608);   // [8][16][3]

    const int tid = threadIdx.x;
    const int bbase = blockIdx.x * NBAT;

    // ---- prologue phase 1: full pose th[b][0..47] ----
    for (int o = tid; o < NBAT * 48; o += 256) {
        int b = o / 48, i = o % 48;
        float acc;
        if (i < 3) {
            acc = theta[(size_t)(bbase + b) * NTHETA + i];
        } else {
            acc = hm[i - 3];
            #pragma unroll
            for (int k = 0; k < 12; ++k)
                acc += theta[(size_t)(bbase + b) * NTHETA + 3 + k] * hc[k * 45 + (i - 3)];
        }
        th[b * 48 + i] = acc;
    }
    __syncthreads();

    // ---- phase 2: Rodrigues (R) + joint positions (JL) per (b, j) ----
    if (tid < NBAT * 16) {
        int b = tid >> 4, j = tid & 15;
        float tx = th[b * 48 + 3 * j], ty = th[b * 48 + 3 * j + 1], tz = th[b * 48 + 3 * j + 2];
        float px = tx + 1e-8f, py = ty + 1e-8f, pz = tz + 1e-8f;
        float ang = sqrtf(px * px + py * py + pz * pz);
        float nx = tx / ang, ny = ty / ang, nz = tz / ang;
        float half = 0.5f * ang;
        float w = cosf(half), s = sinf(half);
        float qx = s * nx, qy = s * ny, qz = s * nz;
        float qn = sqrtf(w * w + qx * qx + qy * qy + qz * qz);
        w /= qn; qx /= qn; qy /= qn; qz /= qn;
        float w2 = w * w, x2 = qx * qx, y2 = qy * qy, z2 = qz * qz;
        float wx = w * qx, wy = w * qy, wz = w * qz;
        float xy = qx * qy, xz = qx * qz, yz = qy * qz;
        float* R = Rsh + (b * 16 + j) * 9;
        R[0] = w2 + x2 - y2 - z2; R[1] = 2.f * xy - 2.f * wz; R[2] = 2.f * wy + 2.f * xz;
        R[3] = 2.f * wz + 2.f * xy; R[4] = w2 - x2 + y2 - z2; R[5] = 2.f * yz - 2.f * wx;
        R[6] = 2.f * xz - 2.f * wy; R[7] = 2.f * wx + 2.f * yz; R[8] = w2 - x2 - y2 + z2;
        #pragma unroll
        for (int c = 0; c < 3; ++c) {
            float acc = Jt[j * 3 + c];
            #pragma unroll
            for (int k = 0; k < NBETA; ++k)
                acc += beta[(size_t)(bbase + b) * NBETA + k] * SJ[k * 48 + j * 3 + c];
            JLs[(b * 16 + j) * 3 + c] = acc;
        }
    }
    __syncthreads();

    // ---- phase 3: kinematic chain -> A_lds; pose_feature -> pf_lds ----
    if (tid < NBAT * 16) {
        int b = tid >> 4, j = tid & 15;
        int path[4]; int d = 0; int i = j;
        while (i >= 0) { path[d++] = i; i = c_par[i]; }
        float GR[9], Gt3[3];
        #pragma unroll
        for (int e = 0; e < 9; ++e) GR[e] = Rsh[(b * 16 + 0) * 9 + e];
        Gt3[0] = JLs[(b * 16) * 3 + 0]; Gt3[1] = JLs[(b * 16) * 3 + 1]; Gt3[2] = JLs[(b * 16) * 3 + 2];
        for (int s2 = d - 2; s2 >= 0; --s2) {
            int i2 = path[s2];
            int pa = c_par[i2];
            float ti0 = JLs[(b * 16 + i2) * 3 + 0] - JLs[(b * 16 + pa) * 3 + 0];
            float ti1 = JLs[(b * 16 + i2) * 3 + 1] - JLs[(b * 16 + pa) * 3 + 1];
            float ti2 = JLs[(b * 16 + i2) * 3 + 2] - JLs[(b * 16 + pa) * 3 + 2];
            const float* Ri = Rsh + (b * 16 + i2) * 9;
            float NR[9], Nt[3];
            #pragma unroll
            for (int r = 0; r < 3; ++r) {
                #pragma unroll
                for (int c = 0; c < 3; ++c) {
                    NR[r * 3 + c] = GR[r * 3 + 0] * Ri[0 * 3 + c]
                                  + GR[r * 3 + 1] * Ri[1 * 3 + c]
                                  + GR[r * 3 + 2] * Ri[2 * 3 + c];
                }
                Nt[r] = GR[r * 3 + 0] * ti0 + GR[r * 3 + 1] * ti1 + GR[r * 3 + 2] * ti2 + Gt3[r];
            }
            #pragma unroll
            for (int e = 0; e < 9; ++e) GR[e] = NR[e];
            Gt3[0] = Nt[0]; Gt3[1] = Nt[1]; Gt3[2] = Nt[2];
        }
        float jx = JLs[(b * 16 + j) * 3 + 0], jy = JLs[(b * 16 + j) * 3 + 1], jz = JLs[(b * 16 + j) * 3 + 2];
        float* A = A_lds + (b * 16 + j) * 12;
        #pragma unroll
        for (int r = 0; r < 3; ++r) {
            A[r * 4 + 0] = GR[r * 3 + 0];
            A[r * 4 + 1] = GR[r * 3 + 1];
            A[r * 4 + 2] = GR[r * 3 + 2];
            A[r * 4 + 3] = Gt3[r] - (GR[r * 3 + 0] * jx + GR[r * 3 + 1] * jy + GR[r * 3 + 2] * jz);
        }
        if (j > 0) {
            #pragma unroll
            for (int e = 0; e < 9; ++e) {
                float dlt = (e == 0 || e == 4 || e == 8) ? 1.f : 0.f;
                pf_lds[((j - 1) * 9 + e) * NBAT + b] = Rsh[(b * 16 + j) * 9 + e] - dlt;
            }
        }
    }
    __syncthreads();   // prologue scratch dead; vertLDS region free

    // ---- main loop: vertices + skinning + joint regression ----
    const int rb = tid & 7;
    const int rj = (tid >> 3) & 15;
    const int half = tid >> 7;
    float jacc0 = 0.f, jacc1 = 0.f, jacc2 = 0.f;

    for (int tile = 0; tile < 4; ++tile) {
        const int v = tile * 256 + tid;
        const bool valid = v < NV;
        float vx[NBAT], vy[NBAT], vz[NBAT];
        float wrow[NJ];

        if (valid) {
            // shape blend, k-outer: 3 loads shared across 8 batches (no 30-reg cache)
            float vt0 = vt[v * 3 + 0], vt1 = vt[v * 3 + 1], vt2 = vt[v * 3 + 2];
            #pragma unroll
            for (int b = 0; b < NBAT; ++b) { vx[b] = vt0; vy[b] = vt1; vz[b] = vt2; }
            #pragma unroll
            for (int k = 0; k < NBETA; ++k) {
                float s0 = sd[k * SD_COLS + v * 3 + 0];
                float s1 = sd[k * SD_COLS + v * 3 + 1];
                float s2 = sd[k * SD_COLS + v * 3 + 2];
                #pragma unroll
                for (int b = 0; b < NBAT; ++b) {
                    float be = beta[(size_t)(bbase + b) * NBETA + k];   // uniform -> s_load
                    vx[b] += be * s0; vy[b] += be * s1; vz[b] += be * s2;
                }
            }
            // pose-blend: pf from LDS broadcast
            for (int p = 0; p < NP; ++p) {
                float p0 = pd[p * SD_COLS + v * 3 + 0];
                float p1 = pd[p * SD_COLS + v * 3 + 1];
                float p2 = pd[p * SD_COLS + v * 3 + 2];
                #pragma unroll
                for (int b = 0; b < NBAT; ++b) {
                    float f = pf_lds[p * NBAT + b];
                    vx[b] += f * p0; vy[b] += f * p1; vz[b] += f * p2;
                }
            }
            #pragma unroll
            for (int j = 0; j < NJ; ++j) wrow[j] = W[v * NJ + j];
        } else {
            #pragma unroll
            for (int b = 0; b < NBAT; ++b) { vx[b] = 0.f; vy[b] = 0.f; vz[b] = 0.f; }
            #pragma unroll
            for (int j = 0; j < NJ; ++j) wrow[j] = 0.f;
        }

        // skinning from LDS-resident A
        #pragma unroll
        for (int b = 0; b < NBAT; ++b) {
            const float* Ab = A_lds + b * 192;
            float ax = 0.f, ay = 0.f, az = 0.f;
            #pragma unroll
            for (int j = 0; j < NJ; ++j) {
                const float* Aj = Ab + j * 12;
                float wj = wrow[j];
                float s0 = Aj[3];  s0 += Aj[0] * vx[b]; s0 += Aj[1]  * vy[b]; s0 += Aj[2]  * vz[b];
                float s1 = Aj[7];  s1 += Aj[4] * vx[b]; s1 += Aj[5]  * vy[b]; s1 += Aj[6]  * vz[b];
                float s2 = Aj[11]; s2 += Aj[8] * vx[b]; s2 += Aj[9]  * vy[b]; s2 += Aj[10] * vz[b];
                ax += wj * s0; ay += wj * s1; az += wj * s2;
            }
            vx[b] = ax; vy[b] = ay; vz[b] = az;
        }

        // finger vertices -> direct output (float32)
        if (valid) {
            int f = (v == 734) ? 0 : (v == 333) ? 1 : (v == 443) ? 2 : (v == 555) ? 3 : (v == 678) ? 4 : -1;
            if (f >= 0) {
                #pragma unroll
                for (int b = 0; b < NBAT; ++b) {
                    size_t o = (size_t)(bbase + b) * 63 + (size_t)(16 + f) * 3;
                    out[o + 0] = vx[b];
                    out[o + 1] = vy[b];
                    out[o + 2] = vz[b];
                }
            }
        }

        // stage vert tile for joint reduction (stride 25: conflict-free)
        #pragma unroll
        for (int b = 0; b < NBAT; ++b) {
            vertLDS[tid * 25 + b * 3 + 0] = vx[b];
            vertLDS[tid * 25 + b * 3 + 1] = vy[b];
            vertLDS[tid * 25 + b * 3 + 2] = vz[b];
        }
        __syncthreads();

        // joints[rb][rj] += sum_v Jr[v][rj] * vert[rb][v]  (each half does 128 vv)
        const int vbase = tile * 256;
        int lim = NV - vbase; if (lim > 256) lim = 256;
        int lo = half * 128;
        int hi = lo + 128; if (hi > lim) hi = lim;
        for (int vv = lo; vv < hi; ++vv) {
            float jr = Jr[(size_t)(vbase + vv) * NJ + rj];
            jacc0 += jr * vertLDS[vv * 25 + rb * 3 + 0];
            jacc1 += jr * vertLDS[vv * 25 + rb * 3 + 1];
            jacc2 += jr * vertLDS[vv * 25 + rb * 3 + 2];
        }
        __syncthreads();
    }

    // combine the two halves' partials via LDS (reuse vertLDS)
    vertLDS[tid * 3 + 0] = jacc0;
    vertLDS[tid * 3 + 1] = jacc1;
    vertLDS[tid * 3 + 2] = jacc2;
    __syncthreads();
    if (tid < 128) {
        float j0 = vertLDS[tid * 3 + 0] + vertLDS[(tid + 128) * 3 + 0];
        float j1 = vertLDS[tid * 3 + 1] + vertLDS[(tid + 128) * 3 + 1];
        float j2 = vertLDS[tid * 3 + 2] + vertLDS[(tid + 128) * 3 + 2];
        size_t o = (size_t)(bbase + rb) * 63 + (size_t)rj * 3;
        out[o + 0] = j0;
        out[o + 1] = j1;
        out[o + 2] = j2;
    }
}

extern "C" void kernel_launch(void* const* d_in, const int* in_sizes, int n_in,
                              void* d_out, int out_size, void* d_ws, size_t ws_size,
                              hipStream_t stream) {
    const float* beta = (const float*)d_in[0];
    const float* theta = (const float*)d_in[1];
    const float* sd   = (const float*)d_in[2];
    const float* pd   = (const float*)d_in[3];
    const float* vt   = (const float*)d_in[4];
    const float* Jr   = (const float*)d_in[5];
    const float* W    = (const float*)d_in[6];
    const float* hm   = (const float*)d_in[7];
    const float* hc   = (const float*)d_in[8];
    float* out = (float*)d_out;

    const int B = in_sizes[0] / NBETA;   // 8192

    float* SJ = (float*)d_ws;            // 480
    float* Jt = SJ + 480;                // 48

    k_prejoint<<<528, 64, 0, stream>>>(sd, vt, Jr, SJ, Jt);
    k_fused<<<B / NBAT, 256, 0, stream>>>(beta, theta, sd, pd, vt, Jr, W, hm, hc, SJ, Jt, out);
}

// Round 14
// 371.733 us; speedup vs baseline: 2.0953x; 1.3947x over previous
//
#include <hip/hip_runtime.h>
#include <hip/hip_bf16.h>

#define NV 778
#define NJ 16
#define NBETA 10
#define NP 135
#define NTHETA 15
#define SD_COLS 2334   // NV*3
#define NBAT 8         // batches per block (computed in 2 passes of 4)

__device__ __constant__ int c_par[16] = {-1,0,1,2,0,4,5,0,7,8,0,10,11,0,13,14};

// ---------------- Kernel 1: SJ[k][j][c] (10x16x3) and Jt[j][c] (16x3) ----------------
__global__ __launch_bounds__(64) void k_prejoint(
    const float* __restrict__ sd, const float* __restrict__ vt,
    const float* __restrict__ Jr, float* __restrict__ SJ, float* __restrict__ Jt)
{
    const int o = blockIdx.x;
    const int t = threadIdx.x;
    float acc = 0.f;
    if (o < 480) {
        int k = o / 48, rem = o % 48, j = rem / 3, c = rem % 3;
        for (int v = t; v < NV; v += 64) acc += sd[k * SD_COLS + v * 3 + c] * Jr[v * NJ + j];
    } else {
        int idx = o - 480, j = idx / 3, c = idx % 3;
        for (int v = t; v < NV; v += 64) acc += vt[v * 3 + c] * Jr[v * NJ + j];
    }
    #pragma unroll
    for (int off = 32; off > 0; off >>= 1) acc += __shfl_down(acc, off);
    if (t == 0) {
        if (o < 480) SJ[o] = acc;
        else Jt[o - 480] = acc;
    }
}

// ---------------- Kernel 2 (fused): pose prologue + vertices + skinning + joints ----
// 1024 blocks x 256 thr, NO min-waves clamp (r9-r11: clamp => allocator dives + spills;
// r12: unconstrained => VGPR 136 > 128 => occupancy 12%). Register pressure reduced
// STRUCTURALLY: main loop runs 2 passes of 4 batches (vx/vy/vz 24->12 regs), pass loop
// pinned with unroll 1 so the compiler can't re-merge pressure. Loads double but are
// L2/L3-resident (r12 FETCH=6.4MB total).
__global__ __launch_bounds__(256) void k_fused(
    const float* __restrict__ beta, const float* __restrict__ theta,
    const float* __restrict__ sd, const float* __restrict__ pd,
    const float* __restrict__ vt, const float* __restrict__ Jr,
    const float* __restrict__ W, const float* __restrict__ hm,
    const float* __restrict__ hc, const float* __restrict__ SJ,
    const float* __restrict__ Jt, float* __restrict__ out)
{
    // LDS plan (23,808 B):
    //   [0, 13312)        vertLDS[256][13]  (staging)  OVERLAYS prologue th/Rsh/JL (7680 B)
    //   [13312, 19456)    A_lds[8][16][12]
    //   [19456, 23808)    pf_lds[135][8]
    __shared__ __align__(16) char smem[13312 + 6144 + 4352];
    float* const vertLDS = (float*)smem;
    float* const A_lds   = (float*)(smem + 13312);
    float* const pf_lds  = (float*)(smem + 13312 + 6144);
    float* const th  = (float*)smem;                   // [8][48]
    float* const Rsh = (float*)(smem + 1536);          // [8][16][9]
    float* const JLs = (float*)(smem + 1536 + 4608);   // [8][16][3]

    const int tid = threadIdx.x;
    const int bbase = blockIdx.x * NBAT;

    // ---- prologue phase 1: full pose th[b][0..47] ----
    for (int o = tid; o < NBAT * 48; o += 256) {
        int b = o / 48, i = o % 48;
        float acc;
        if (i < 3) {
            acc = theta[(size_t)(bbase + b) * NTHETA + i];
        } else {
            acc = hm[i - 3];
            #pragma unroll
            for (int k = 0; k < 12; ++k)
                acc += theta[(size_t)(bbase + b) * NTHETA + 3 + k] * hc[k * 45 + (i - 3)];
        }
        th[b * 48 + i] = acc;
    }
    __syncthreads();

    // ---- phase 2: Rodrigues (R) + joint positions (JL) per (b, j) ----
    if (tid < NBAT * 16) {
        int b = tid >> 4, j = tid & 15;
        float tx = th[b * 48 + 3 * j], ty = th[b * 48 + 3 * j + 1], tz = th[b * 48 + 3 * j + 2];
        float px = tx + 1e-8f, py = ty + 1e-8f, pz = tz + 1e-8f;
        float ang = sqrtf(px * px + py * py + pz * pz);
        float nx = tx / ang, ny = ty / ang, nz = tz / ang;
        float half = 0.5f * ang;
        float w = cosf(half), s = sinf(half);
        float qx = s * nx, qy = s * ny, qz = s * nz;
        float qn = sqrtf(w * w + qx * qx + qy * qy + qz * qz);
        w /= qn; qx /= qn; qy /= qn; qz /= qn;
        float w2 = w * w, x2 = qx * qx, y2 = qy * qy, z2 = qz * qz;
        float wx = w * qx, wy = w * qy, wz = w * qz;
        float xy = qx * qy, xz = qx * qz, yz = qy * qz;
        float* R = Rsh + (b * 16 + j) * 9;
        R[0] = w2 + x2 - y2 - z2; R[1] = 2.f * xy - 2.f * wz; R[2] = 2.f * wy + 2.f * xz;
        R[3] = 2.f * wz + 2.f * xy; R[4] = w2 - x2 + y2 - z2; R[5] = 2.f * yz - 2.f * wx;
        R[6] = 2.f * xz - 2.f * wy; R[7] = 2.f * wx + 2.f * yz; R[8] = w2 - x2 - y2 + z2;
        #pragma unroll
        for (int c = 0; c < 3; ++c) {
            float acc = Jt[j * 3 + c];
            #pragma unroll
            for (int k = 0; k < NBETA; ++k)
                acc += beta[(size_t)(bbase + b) * NBETA + k] * SJ[k * 48 + j * 3 + c];
            JLs[(b * 16 + j) * 3 + c] = acc;
        }
    }
    __syncthreads();

    // ---- phase 3: kinematic chain -> A_lds; pose_feature -> pf_lds ----
    if (tid < NBAT * 16) {
        int b = tid >> 4, j = tid & 15;
        int path[4]; int d = 0; int i = j;
        while (i >= 0) { path[d++] = i; i = c_par[i]; }
        float GR[9], Gt3[3];
        #pragma unroll
        for (int e = 0; e < 9; ++e) GR[e] = Rsh[(b * 16 + 0) * 9 + e];
        Gt3[0] = JLs[(b * 16) * 3 + 0]; Gt3[1] = JLs[(b * 16) * 3 + 1]; Gt3[2] = JLs[(b * 16) * 3 + 2];
        for (int s2 = d - 2; s2 >= 0; --s2) {
            int i2 = path[s2];
            int pa = c_par[i2];
            float ti0 = JLs[(b * 16 + i2) * 3 + 0] - JLs[(b * 16 + pa) * 3 + 0];
            float ti1 = JLs[(b * 16 + i2) * 3 + 1] - JLs[(b * 16 + pa) * 3 + 1];
            float ti2 = JLs[(b * 16 + i2) * 3 + 2] - JLs[(b * 16 + pa) * 3 + 2];
            const float* Ri = Rsh + (b * 16 + i2) * 9;
            float NR[9], Nt[3];
            #pragma unroll
            for (int r = 0; r < 3; ++r) {
                #pragma unroll
                for (int c = 0; c < 3; ++c) {
                    NR[r * 3 + c] = GR[r * 3 + 0] * Ri[0 * 3 + c]
                                  + GR[r * 3 + 1] * Ri[1 * 3 + c]
                                  + GR[r * 3 + 2] * Ri[2 * 3 + c];
                }
                Nt[r] = GR[r * 3 + 0] * ti0 + GR[r * 3 + 1] * ti1 + GR[r * 3 + 2] * ti2 + Gt3[r];
            }
            #pragma unroll
            for (int e = 0; e < 9; ++e) GR[e] = NR[e];
            Gt3[0] = Nt[0]; Gt3[1] = Nt[1]; Gt3[2] = Nt[2];
        }
        float jx = JLs[(b * 16 + j) * 3 + 0], jy = JLs[(b * 16 + j) * 3 + 1], jz = JLs[(b * 16 + j) * 3 + 2];
        float* A = A_lds + (b * 16 + j) * 12;
        #pragma unroll
        for (int r = 0; r < 3; ++r) {
            A[r * 4 + 0] = GR[r * 3 + 0];
            A[r * 4 + 1] = GR[r * 3 + 1];
            A[r * 4 + 2] = GR[r * 3 + 2];
            A[r * 4 + 3] = Gt3[r] - (GR[r * 3 + 0] * jx + GR[r * 3 + 1] * jy + GR[r * 3 + 2] * jz);
        }
        if (j > 0) {
            #pragma unroll
            for (int e = 0; e < 9; ++e) {
                float dlt = (e == 0 || e == 4 || e == 8) ? 1.f : 0.f;
                pf_lds[((j - 1) * 9 + e) * NBAT + b] = Rsh[(b * 16 + j) * 9 + e] - dlt;
            }
        }
    }
    __syncthreads();   // prologue scratch dead; vertLDS region free

    // ---- main loop: 2 passes x 4 batches ----
    const int rb = tid & 3;            // batch within pass
    const int rj = (tid >> 2) & 15;    // joint
    const int quarter = tid >> 6;      // 64-row slice of each 256-row tile

    #pragma unroll 1
    for (int h = 0; h < 2; ++h) {
        const int bb = h * 4;
        float jacc0 = 0.f, jacc1 = 0.f, jacc2 = 0.f;

        #pragma unroll 1
        for (int tile = 0; tile < 4; ++tile) {
            const int vbase = tile * 256;
            const int v = vbase + tid;
            const bool valid = v < NV;
            float vx[4], vy[4], vz[4];
            float wrow[NJ];

            if (valid) {
                float vt0 = vt[v * 3 + 0], vt1 = vt[v * 3 + 1], vt2 = vt[v * 3 + 2];
                #pragma unroll
                for (int b = 0; b < 4; ++b) { vx[b] = vt0; vy[b] = vt1; vz[b] = vt2; }
                #pragma unroll
                for (int k = 0; k < NBETA; ++k) {
                    float s0 = sd[k * SD_COLS + v * 3 + 0];
                    float s1 = sd[k * SD_COLS + v * 3 + 1];
                    float s2 = sd[k * SD_COLS + v * 3 + 2];
                    #pragma unroll
                    for (int b = 0; b < 4; ++b) {
                        float be = beta[(size_t)(bbase + bb + b) * NBETA + k];   // uniform
                        vx[b] += be * s0; vy[b] += be * s1; vz[b] += be * s2;
                    }
                }
                for (int p = 0; p < NP; ++p) {
                    float p0 = pd[p * SD_COLS + v * 3 + 0];
                    float p1 = pd[p * SD_COLS + v * 3 + 1];
                    float p2 = pd[p * SD_COLS + v * 3 + 2];
                    #pragma unroll
                    for (int b = 0; b < 4; ++b) {
                        float f = pf_lds[p * NBAT + bb + b];
                        vx[b] += f * p0; vy[b] += f * p1; vz[b] += f * p2;
                    }
                }
                #pragma unroll
                for (int j = 0; j < NJ; ++j) wrow[j] = W[v * NJ + j];
            } else {
                #pragma unroll
                for (int b = 0; b < 4; ++b) { vx[b] = 0.f; vy[b] = 0.f; vz[b] = 0.f; }
                #pragma unroll
                for (int j = 0; j < NJ; ++j) wrow[j] = 0.f;
            }

            // skinning from LDS-resident A
            #pragma unroll
            for (int b = 0; b < 4; ++b) {
                const float* Ab = A_lds + (bb + b) * 192;
                float ax = 0.f, ay = 0.f, az = 0.f;
                #pragma unroll
                for (int j = 0; j < NJ; ++j) {
                    const float* Aj = Ab + j * 12;
                    float wj = wrow[j];
                    float s0 = Aj[3];  s0 += Aj[0] * vx[b]; s0 += Aj[1]  * vy[b]; s0 += Aj[2]  * vz[b];
                    float s1 = Aj[7];  s1 += Aj[4] * vx[b]; s1 += Aj[5]  * vy[b]; s1 += Aj[6]  * vz[b];
                    float s2 = Aj[11]; s2 += Aj[8] * vx[b]; s2 += Aj[9]  * vy[b]; s2 += Aj[10] * vz[b];
                    ax += wj * s0; ay += wj * s1; az += wj * s2;
                }
                vx[b] = ax; vy[b] = ay; vz[b] = az;
            }

            // finger vertices -> direct output (float32)
            if (valid) {
                int f = (v == 734) ? 0 : (v == 333) ? 1 : (v == 443) ? 2 : (v == 555) ? 3 : (v == 678) ? 4 : -1;
                if (f >= 0) {
                    #pragma unroll
                    for (int b = 0; b < 4; ++b) {
                        size_t o = (size_t)(bbase + bb + b) * 63 + (size_t)(16 + f) * 3;
                        out[o + 0] = vx[b];
                        out[o + 1] = vy[b];
                        out[o + 2] = vz[b];
                    }
                }
            }

            // stage vert tile (stride 13, odd -> 2-way max, free)
            #pragma unroll
            for (int b = 0; b < 4; ++b) {
                vertLDS[tid * 13 + b * 3 + 0] = vx[b];
                vertLDS[tid * 13 + b * 3 + 1] = vy[b];
                vertLDS[tid * 13 + b * 3 + 2] = vz[b];
            }
            __syncthreads();

            // joints[rb][rj] += sum_v Jr[v][rj] * vert[rb][v]  (quarter does 64 rows;
            // vv is wave-uniform -> vertLDS reads are 16-lane broadcasts, Jr one segment)
            int lim = NV - vbase; if (lim > 256) lim = 256;
            int lo = quarter * 64;
            int hi = lo + 64; if (hi > lim) hi = lim;
            for (int vv = lo; vv < hi; ++vv) {
                float jr = Jr[(size_t)(vbase + vv) * NJ + rj];
                jacc0 += jr * vertLDS[vv * 13 + rb * 3 + 0];
                jacc1 += jr * vertLDS[vv * 13 + rb * 3 + 1];
                jacc2 += jr * vertLDS[vv * 13 + rb * 3 + 2];
            }
            __syncthreads();
        }

        // combine the 4 quarters' partials via LDS (768 floats in vertLDS region)
        vertLDS[tid * 3 + 0] = jacc0;
        vertLDS[tid * 3 + 1] = jacc1;
        vertLDS[tid * 3 + 2] = jacc2;
        __syncthreads();
        if (tid < 64) {
            float j0 = 0.f, j1 = 0.f, j2 = 0.f;
            #pragma unroll
            for (int q = 0; q < 4; ++q) {
                j0 += vertLDS[(tid + q * 64) * 3 + 0];
                j1 += vertLDS[(tid + q * 64) * 3 + 1];
                j2 += vertLDS[(tid + q * 64) * 3 + 2];
            }
            size_t o = (size_t)(bbase + bb + rb) * 63 + (size_t)rj * 3;
            out[o + 0] = j0;
            out[o + 1] = j1;
            out[o + 2] = j2;
        }
        __syncthreads();   // protect vertLDS before next pass re-stages
    }
}

extern "C" void kernel_launch(void* const* d_in, const int* in_sizes, int n_in,
                              void* d_out, int out_size, void* d_ws, size_t ws_size,
                              hipStream_t stream) {
    const float* beta = (const float*)d_in[0];
    const float* theta = (const float*)d_in[1];
    const float* sd   = (const float*)d_in[2];
    const float* pd   = (const float*)d_in[3];
    const float* vt   = (const float*)d_in[4];
    const float* Jr   = (const float*)d_in[5];
    const float* W    = (const float*)d_in[6];
    const float* hm   = (const float*)d_in[7];
    const float* hc   = (const float*)d_in[8];
    float* out = (float*)d_out;

    const int B = in_sizes[0] / NBETA;   // 8192

    float* SJ = (float*)d_ws;            // 480
    float* Jt = SJ + 480;                // 48

    k_prejoint<<<528, 64, 0, stream>>>(sd, vt, Jr, SJ, Jt);
    k_fused<<<B / NBAT, 256, 0, stream>>>(beta, theta, sd, pd, vt, Jr, W, hm, hc, SJ, Jt, out);
}